// Round 14
// baseline (186.701 us; speedup 1.0000x reference)
//
#include <hip/hip_runtime.h>

typedef unsigned short u16;
typedef unsigned int u32;
typedef __attribute__((ext_vector_type(8))) short short8;  // 8 bf16 (4 VGPRs)
typedef __attribute__((ext_vector_type(4))) float f32x4;   // MFMA acc
typedef __attribute__((ext_vector_type(4))) u32 u32x4;
typedef _Float16 f16x2 __attribute__((ext_vector_type(2)));

// ---- bf16 helpers ----
__device__ __forceinline__ float bf2f(u16 v) {
  return __uint_as_float(((u32)v) << 16);
}
__device__ __forceinline__ u16 f2bf(float f) {
  u32 u = __float_as_uint(f);
  return (u16)((u + 0x7fffu + ((u >> 16) & 1u)) >> 16);  // RNE
}
__device__ __forceinline__ u32 pk2(float lo, float hi) {
  return (u32)f2bf(lo) | ((u32)f2bf(hi) << 16);
}

// flagged input loads (fp32 vs bf16, wave-uniform branch)
__device__ __forceinline__ float ld1in(const void* p, size_t i, bool f32) {
  return f32 ? ((const float*)p)[i] : bf2f(((const u16*)p)[i]);
}
__device__ __forceinline__ float4 ld4in(const void* p, size_t i, bool f32) {
  if (f32) return *(const float4*)((const float*)p + i);
  ushort4 u = *(const ushort4*)((const u16*)p + i);
  return make_float4(bf2f(u.x), bf2f(u.y), bf2f(u.z), bf2f(u.w));
}

// ws loads (ws is bf16 — forced since round 10)
__device__ __forceinline__ uint4 ld8ws_pk(const u16* p, size_t i) {
  return *(const uint4*)(p + i);
}

// B=4, S=1024, H=8, DH=64, D=512, NUM_RPR=11
// ws: [int flag][pad->1024B][qh|kh|vh] bf16, each [B*H=32][S=1024][64]
// BANKED LESSONS: (r6/7) no LDS float atomics (NaN). (r8) 128x128 proj tile
// neutral-to-worse. (r9) K/V dbuf + rid-from-global. (r10) bf16 ws. (r13)
// fdot2-bins + packed-P + exp2-fold + no C->D barrier: 73.7->60.0us. (r14/15)
// 8-wave IN-BLOCK k-split DEAD END; launch_bounds 2nd arg = WG/CU VGPR cap.
// (r16) LDS slack useless: occupancy GRID-capped at 2 blocks/CU. (r18)
// conflicts (4472832, invariant) live in the qrpr gather (16 lanes of a
// quad-group hammer ONE qrpr row); K/V chunk swizzle neutral. (r22) rid
// prefetch -6%. (r23) cross-block KV-split dead end (+37us). (r24) host-side
// dtype neutral (~120us non-attn time unexplained, proj <60us).
// ROUND 25: SWAPPED QK^T (T12 mechanism). mfma(K,Q) -> lane owns ONE q-row
// (q=wvi*16+col) with S along k. (a) P stays in REGISTERS: lane's 16 p's map
// onto its own PV A-frag via k' = quad*8+(c&1)*4+reg+(c>>1)*32 (bijection);
// ps LDS round-trip (4 writes + 2 b128 reads + lgkm chain/tile) deleted.
// (b) qrpr gather rows now per-lane distinct (row=col) -> bank spread.
// (c) rid: 16 scalar -> 4 int4 loads. (d) bins 44 -> 11 regs. V staging
// k'-permuted via row-pair base vr0m (write pattern unchanged). PV output
// layout == old epilogue layout (derived from documented C/D mapping).
// Epilogue: bins reduce over quads (shfl 16,32) + wave-private LDS transpose
// in dead qps space (no barrier; r13 precedent).

// ---------------------------------------------------------------------------
// Kernel 0: dtype detector (fallback only; validated r14/r15).
// ---------------------------------------------------------------------------
__global__ void rpr_detect_kernel(const u16* __restrict__ q, int* __restrict__ flag) {
  __shared__ int cnt4[4];
  int t = threadIdx.x, c = 0;
  for (int i = t; i < 8192; i += 256) {
    unsigned e = (q[i] >> 7) & 0xff;
    c += (e >= 0xC0) ? 1 : 0;
  }
#pragma unroll
  for (int off = 1; off < 64; off <<= 1) c += __shfl_xor(c, off);
  if ((t & 63) == 0) cnt4[t >> 6] = c;
  __syncthreads();
  if (t == 0) *flag = (cnt4[0] + cnt4[1] + cnt4[2] + cnt4[3] > 128) ? 1 : 0;
}

// ---------------------------------------------------------------------------
// Kernel 1: QKV projection via bf16 MFMA, 64x64 tile, BK=32.
// Unchanged (r13-validated dbuf version + hflag).
// ---------------------------------------------------------------------------
template <typename WT>
__global__ __launch_bounds__(256, 2) void rpr_proj_mfma(
    const void* __restrict__ xq, const void* __restrict__ xk, const void* __restrict__ xv,
    const void* __restrict__ wqp, const void* __restrict__ wkp, const void* __restrict__ wvp,
    const void* __restrict__ bqp, const void* __restrict__ bkp, const void* __restrict__ bvp,
    WT* __restrict__ ws, const int* __restrict__ flagp, int hflag) {
  const bool f32 = (hflag >= 0) ? (hflag != 0) : (*flagp != 0);
  const int z = blockIdx.z;
  const void* __restrict__ X = (z == 0) ? xq : (z == 1) ? xk : xv;
  const void* __restrict__ W = (z == 0) ? wqp : (z == 1) ? wkp : wvp;
  const void* __restrict__ Bb = (z == 0) ? bqp : (z == 1) ? bkp : bvp;
  WT* __restrict__ O = ws + (size_t)z * (4096u * 512u);

  __shared__ u32 as32[2][64][20];  // A[m][k] bf16 u32-paired, dbuf
  __shared__ u32 bs32[2][64][20];  // B^T[n][k] bf16 u32-paired, dbuf

  const int t = threadIdx.x;
  const int wvi = t >> 6, lane = t & 63;
  const int quad = lane >> 4, col = lane & 15;
  const int m0 = blockIdx.y * 64, n0 = blockIdx.x * 64;
  const int am = t >> 2, akc = t & 3;          // A map: row, k-chunk of 8
  const int bkx = t & 15, bnx = (t >> 4) * 4;  // B map: k-pair, n-group of 4

  f32x4 acc[4] = {{0.f, 0.f, 0.f, 0.f}, {0.f, 0.f, 0.f, 0.f},
                  {0.f, 0.f, 0.f, 0.f}, {0.f, 0.f, 0.f, 0.f}};

  // tile loaders: global k0-slice -> registers (uniform dtype branch)
  auto loadA = [&](int k0, uint4& ra) {
    if (!f32) {
      ra = *(const uint4*)((const u16*)X + (size_t)(m0 + am) * 512 + k0 + akc * 8);
    } else {
      const float* xf = (const float*)X + (size_t)(m0 + am) * 512 + k0 + akc * 8;
      float4 a = *(const float4*)xf, b = *(const float4*)(xf + 4);
      ra.x = pk2(a.x, a.y); ra.y = pk2(a.z, a.w);
      ra.z = pk2(b.x, b.y); ra.w = pk2(b.z, b.w);
    }
  };
  auto loadB = [&](int k0, uint4& rb) {
    if (!f32) {
      const u16* w0 = (const u16*)W + (size_t)(k0 + 2 * bkx) * 512 + n0 + bnx;
      ushort4 r0 = *(const ushort4*)w0;
      ushort4 r1 = *(const ushort4*)(w0 + 512);
      rb.x = (u32)r0.x | ((u32)r1.x << 16);
      rb.y = (u32)r0.y | ((u32)r1.y << 16);
      rb.z = (u32)r0.z | ((u32)r1.z << 16);
      rb.w = (u32)r0.w | ((u32)r1.w << 16);
    } else {
      float4 r0 = ld4in(W, (size_t)(k0 + 2 * bkx) * 512 + n0 + bnx, true);
      float4 r1 = ld4in(W, (size_t)(k0 + 2 * bkx + 1) * 512 + n0 + bnx, true);
      rb.x = pk2(r0.x, r1.x);
      rb.y = pk2(r0.y, r1.y);
      rb.z = pk2(r0.z, r1.z);
      rb.w = pk2(r0.w, r1.w);
    }
  };

  // preload tile 0 -> buffer 0
  {
    uint4 ra, rb;
    loadA(0, ra);
    loadB(0, rb);
    *(uint4*)&as32[0][am][akc * 4] = ra;
    bs32[0][bnx + 0][bkx] = rb.x;
    bs32[0][bnx + 1][bkx] = rb.y;
    bs32[0][bnx + 2][bkx] = rb.z;
    bs32[0][bnx + 3][bkx] = rb.w;
  }
  __syncthreads();

  for (int it = 0; it < 16; ++it) {
    const int cur = it & 1;
    // prefetch next tile into registers (hidden under MFMA below)
    uint4 ra, rb;
    if (it < 15) {
      loadA((it + 1) * 32, ra);
      loadB((it + 1) * 32, rb);
    }
    // A-frag: A[m=lane&15][k=quad*8+j]
    short8 aF = *(const short8*)((const u16*)&as32[cur][wvi * 16 + col][0] + quad * 8);
#pragma unroll
    for (int c = 0; c < 4; ++c) {
      // B-frag: B[k=quad*8+j][n=lane&15] read from B^T row n
      short8 bF = *(const short8*)((const u16*)&bs32[cur][c * 16 + col][0] + quad * 8);
      acc[c] = __builtin_amdgcn_mfma_f32_16x16x32_bf16(aF, bF, acc[c], 0, 0, 0);
    }
    // write prefetched tile into the alternate buffer
    if (it < 15) {
      *(uint4*)&as32[1 - cur][am][akc * 4] = ra;
      bs32[1 - cur][bnx + 0][bkx] = rb.x;
      bs32[1 - cur][bnx + 1][bkx] = rb.y;
      bs32[1 - cur][bnx + 2][bkx] = rb.z;
      bs32[1 - cur][bnx + 3][bkx] = rb.w;
    }
    __syncthreads();  // alt buffer visible; cur reads done before next overwrite
  }

  const int h = blockIdx.x;  // n0 >> 6
#pragma unroll
  for (int c = 0; c < 4; ++c) {
    float bias = ld1in(Bb, (size_t)(n0 + c * 16 + col), f32);
#pragma unroll
    for (int reg = 0; reg < 4; ++reg) {
      int m = m0 + wvi * 16 + quad * 4 + reg;  // C layout: row = quad*4+reg
      int bb = m >> 10, s = m & 1023;
      O[((size_t)((bb * 8 + h) * 1024 + s)) * 64 + c * 16 + col] =
          f2bf(acc[c][reg] + bias);
    }
  }
}

// ---------------------------------------------------------------------------
// Kernel 2: MFMA flash attention with RPR — ROUND-25 swapped-QK^T version.
// Lane q-row = wvi*16+col; P in registers; V^T k'-permuted.
// ---------------------------------------------------------------------------
template <typename WT>
__global__ __launch_bounds__(256, 2) void rpr_attn_mfma(
    const WT* __restrict__ qkv, const int* __restrict__ rpr,
    const void* __restrict__ krpr, void* __restrict__ out,
    const int* __restrict__ flagp, int hflag) {
  const bool f32 = (hflag >= 0) ? (hflag != 0) : (*flagp != 0);
  const int bh = blockIdx.y, q0 = blockIdx.x * 64;
  const int b = bh >> 3, h = bh & 7;
  const WT* __restrict__ qh = qkv + (size_t)bh * 65536;
  const WT* __restrict__ kh = qkv + (size_t)(32 + bh) * 65536;
  const WT* __restrict__ vh = qkv + (size_t)(64 + bh) * 65536;

  __shared__ alignas(16) u16 qps[64][72];  // Q (prologue), binT (epilogue)
  __shared__ u16 ks[2][64][72];    // K-tile [key][d], dbuf (direct layout)
  __shared__ u32 vs32[2][64][36];  // V^T [d][k'-slot] u32, dbuf, k'-permuted
  __shared__ float krl[11][64];    // krpr fp32 (value-side epilogue)
  __shared__ float qrpr[64][12];   // (q.krpr[r])*0.125*log2e (pre-scaled)
  // total 51968 B

  const int t = threadIdx.x;
  const int wvi = t >> 6, lane = t & 63;
  const int quad = lane >> 4, col = lane & 15;
  const int sr = t >> 2, sc4 = (t & 3) * 16;  // Q/K staging map
  const int kp = t & 31, dg = (t >> 5) * 8;   // V staging map
  // k'-permute: u32 slot kp of a V^T row holds V rows {vr0m, vr0m+1}
  // (k'=2kp: reg=2(kp&1), c=((kp>>1)&1)+2((kp>>4)&1), quad_k=(kp>>2)&3)
  const int vr0m = (((kp >> 1) & 1) + 2 * ((kp >> 4) & 1)) * 16 +
                   ((kp >> 2) & 3) * 4 + 2 * (kp & 1);
  const int myq = wvi * 16 + col;        // this lane's q-row (wave-local)
  const int row0 = wvi * 16 + quad * 4;  // ctx output rows base

  // ---- one-time staging (krl, Q, K/V tile 0 -> buffer 0) ----
  for (int i = t; i < 704; i += 256)
    krl[i >> 6][i & 63] = f32 ? ((const float*)krpr)[i] : bf2f(((const u16*)krpr)[i]);
  {
    size_t base = (size_t)(q0 + sr) * 64 + sc4;
    *(uint4*)&qps[sr][sc4] = ld8ws_pk(qh, base);
    *(uint4*)&qps[sr][sc4 + 8] = ld8ws_pk(qh, base + 8);
  }
  {
    size_t kb = (size_t)sr * 64 + sc4;
    *(uint4*)&ks[0][sr][sc4] = ld8ws_pk(kh, kb);
    *(uint4*)&ks[0][sr][sc4 + 8] = ld8ws_pk(kh, kb + 8);
    size_t vb = (size_t)vr0m * 64 + dg;
    uint4 va = ld8ws_pk(vh, vb), vbb = ld8ws_pk(vh, vb + 64);  // rows vr0m, +1
    vs32[0][dg + 0][kp] = (va.x & 0xffffu) | (vbb.x << 16);
    vs32[0][dg + 1][kp] = (va.x >> 16) | (vbb.x & 0xffff0000u);
    vs32[0][dg + 2][kp] = (va.y & 0xffffu) | (vbb.y << 16);
    vs32[0][dg + 3][kp] = (va.y >> 16) | (vbb.y & 0xffff0000u);
    vs32[0][dg + 4][kp] = (va.z & 0xffffu) | (vbb.z << 16);
    vs32[0][dg + 5][kp] = (va.z >> 16) | (vbb.z & 0xffff0000u);
    vs32[0][dg + 6][kp] = (va.w & 0xffffu) | (vbb.w << 16);
    vs32[0][dg + 7][kp] = (va.w >> 16) | (vbb.w & 0xffff0000u);
  }
  __syncthreads();
  // qrpr[row][r]: thread -> row t>>2, r in {t&3, +4, +8}; pre-scaled
  {
    const float SC = 0.18033688011112042f;  // 0.125 * log2(e)
    int r = t >> 2, rb = t & 3;
    float d0 = 0.f, d1 = 0.f, d2 = 0.f;
    for (int d = 0; d < 64; ++d) {
      float qv = bf2f(qps[r][d]);
      d0 = fmaf(qv, krl[rb][d], d0);
      d1 = fmaf(qv, krl[rb + 4][d], d1);
      if (rb < 3) d2 = fmaf(qv, krl[rb + 8][d], d2);
    }
    qrpr[r][rb] = d0 * SC;
    qrpr[r][rb + 4] = d1 * SC;
    if (rb < 3) qrpr[r][rb + 8] = d2 * SC;
  }
  // Q frags (B-operand for swapped MFMA): Q[myq][d = quad*8+j], two d-halves
  short8 qA0, qA1;
  {
    const u16* qrow = &qps[myq][0];
    qA0 = *(const short8*)(qrow + quad * 8);
    qA1 = *(const short8*)(qrow + 32 + quad * 8);
  }
  __syncthreads();  // qrpr + frags consumed; qps region free (binT epilogue)

  float bins[11] = {};  // single-row bins (lane's q-row) — was 44 regs
  f32x4 ctx[4] = {{0.f, 0.f, 0.f, 0.f}, {0.f, 0.f, 0.f, 0.f},
                  {0.f, 0.f, 0.f, 0.f}, {0.f, 0.f, 0.f, 0.f}};

  for (int kt = 0; kt < 16; ++kt) {
    const int cur = kt & 1;
    // (A) prefetch next K/V tile into registers (hidden under B-D)
    uint4 pk0, pk1, pva, pvb;
    if (kt < 15) {
      size_t kb = (size_t)((kt + 1) * 64 + sr) * 64 + sc4;
      pk0 = ld8ws_pk(kh, kb);
      pk1 = ld8ws_pk(kh, kb + 8);
      size_t vb = (size_t)((kt + 1) * 64 + vr0m) * 64 + dg;
      pva = ld8ws_pk(vh, vb);
      pvb = ld8ws_pk(vh, vb + 64);
    }
    // rid: 4 x int4, contiguous keys for this lane's q-row (L2-hot)
    int4 rid4[4];
    {
      const int* rbase = rpr + (size_t)(q0 + myq) * 1024 + kt * 64;
#pragma unroll
      for (int c = 0; c < 4; ++c)
        rid4[c] = *(const int4*)(rbase + c * 16 + quad * 4);
    }
    // (B) S^T = K·Q^T via MFMA: sc[c][reg] = S[myq][kt*64 + c*16 + quad*4+reg]
    f32x4 sc[4];
#pragma unroll
    for (int c = 0; c < 4; ++c) {
      const u16* kb = &ks[cur][c * 16 + col][0];
      short8 kB0 = *(const short8*)(kb + quad * 8);
      short8 kB1 = *(const short8*)(kb + 32 + quad * 8);
      f32x4 a = {0.f, 0.f, 0.f, 0.f};
      a = __builtin_amdgcn_mfma_f32_16x16x32_bf16(kB0, qA0, a, 0, 0, 0);
      a = __builtin_amdgcn_mfma_f32_16x16x32_bf16(kB1, qA1, a, 0, 0, 0);
      sc[c] = a;
    }
    // (C) p = exp2(fma(s, SC, qrpr[myq][rid])); bins via fdot2; P -> regs.
    //     k' = quad*8 + (c&1)*4 + reg + (c>>1)*32  (bijection on [0,64))
    const float* qr = &qrpr[myq][0];
    u32 paw[8];
#pragma unroll
    for (int c = 0; c < 4; ++c) {
      int r0 = rid4[c].x, r1 = rid4[c].y, r2 = rid4[c].z, r3 = rid4[c].w;
      float p0, p1, p2, p3;
      {
        float x0 = fmaf(sc[c][0], 0.18033688011112042f, qr[r0]);
        float x1 = fmaf(sc[c][1], 0.18033688011112042f, qr[r1]);
        float x2 = fmaf(sc[c][2], 0.18033688011112042f, qr[r2]);
        float x3 = fmaf(sc[c][3], 0.18033688011112042f, qr[r3]);
        asm("v_exp_f32 %0, %1" : "=v"(p0) : "v"(x0));
        asm("v_exp_f32 %0, %1" : "=v"(p1) : "v"(x1));
        asm("v_exp_f32 %0, %1" : "=v"(p2) : "v"(x2));
        asm("v_exp_f32 %0, %1" : "=v"(p3) : "v"(x3));
      }
      f16x2 ph01 = __builtin_bit_cast(f16x2, __builtin_amdgcn_cvt_pkrtz(p0, p1));
      f16x2 ph23 = __builtin_bit_cast(f16x2, __builtin_amdgcn_cvt_pkrtz(p2, p3));
      u32 m01 = (1u << (u32)r0) | (0x10000u << (u32)r1);
      u32 m23 = (1u << (u32)r2) | (0x10000u << (u32)r3);
#pragma unroll
      for (int r = 0; r < 11; ++r) {
        u32 s01 = ((m01 >> r) & 0x00010001u) * 0x3C00u;
        u32 s23 = ((m23 >> r) & 0x00010001u) * 0x3C00u;
        bins[r] = __builtin_amdgcn_fdot2(ph01, __builtin_bit_cast(f16x2, s01),
                                         bins[r], false);
        bins[r] = __builtin_amdgcn_fdot2(ph23, __builtin_bit_cast(f16x2, s23),
                                         bins[r], false);
      }
      u32 w0, w1;
      asm("v_cvt_pk_bf16_f32 %0, %1, %2" : "=v"(w0) : "v"(p0), "v"(p1));
      asm("v_cvt_pk_bf16_f32 %0, %1, %2" : "=v"(w1) : "v"(p2), "v"(p3));
      paw[2 * c] = w0;
      paw[2 * c + 1] = w1;
    }
    u32x4 pw0 = {paw[0], paw[1], paw[2], paw[3]};
    u32x4 pw1 = {paw[4], paw[5], paw[6], paw[7]};
    short8 pa0 = __builtin_bit_cast(short8, pw0);  // k' in [quad*8, +8)
    short8 pa1 = __builtin_bit_cast(short8, pw1);  // k' in [32+quad*8, +8)

    // (D) PV: ctx[c][reg] += P[row0+reg-ish]·V — output layout = old epilogue
    #pragma unroll
    for (int c = 0; c < 4; ++c) {
      const u16* vrow = (const u16*)&vs32[cur][c * 16 + col][0];
      short8 vB0 = *(const short8*)(vrow + quad * 8);
      short8 vB1 = *(const short8*)(vrow + 32 + quad * 8);
      ctx[c] = __builtin_amdgcn_mfma_f32_16x16x32_bf16(pa0, vB0, ctx[c], 0, 0, 0);
      ctx[c] = __builtin_amdgcn_mfma_f32_16x16x32_bf16(pa1, vB1, ctx[c], 0, 0, 0);
    }
    // (E) write prefetched tile into the alternate buffer
    if (kt < 15) {
      *(uint4*)&ks[1 - cur][sr][sc4] = pk0;
      *(uint4*)&ks[1 - cur][sr][sc4 + 8] = pk1;
      vs32[1 - cur][dg + 0][kp] = (pva.x & 0xffffu) | (pvb.x << 16);
      vs32[1 - cur][dg + 1][kp] = (pva.x >> 16) | (pvb.x & 0xffff0000u);
      vs32[1 - cur][dg + 2][kp] = (pva.y & 0xffffu) | (pvb.y << 16);
      vs32[1 - cur][dg + 3][kp] = (pva.y >> 16) | (pvb.y & 0xffff0000u);
      vs32[1 - cur][dg + 4][kp] = (pva.z & 0xffffu) | (pvb.z << 16);
      vs32[1 - cur][dg + 5][kp] = (pva.z >> 16) | (pvb.z & 0xffff0000u);
      vs32[1 - cur][dg + 6][kp] = (pva.w & 0xffffu) | (pvb.w << 16);
      vs32[1 - cur][dg + 7][kp] = (pva.w >> 16) | (pvb.w & 0xffff0000u);
    }
    __syncthreads();  // next tile's frag reads see the new buffer
  }

  // ---- epilogue ----
  // bins complete for row myq: reduce over the 4 quads (lane bits 4-5)
#pragma unroll
  for (int off = 16; off < 64; off <<= 1) {
#pragma unroll
    for (int r = 0; r < 11; ++r) bins[r] += __shfl_xor(bins[r], off);
  }
  // transpose bins rows (col-owned) -> reg-owned via wave-private LDS (qps)
  float* binT = (float*)(&qps[0][0]) + wvi * (16 * 12);
  if (quad == 0) {
#pragma unroll
    for (int r = 0; r < 11; ++r) binT[col * 12 + r] = bins[r];
  }
  // wave-internal ds ordering: compiler-inserted lgkmcnt (r13 precedent)
#pragma unroll
  for (int reg = 0; reg < 4; ++reg) {
    float bt[11], l = 0.f;
#pragma unroll
    for (int r = 0; r < 11; ++r) {
      bt[r] = binT[(quad * 4 + reg) * 12 + r];
      l += bt[r];
    }
    float inv = 1.f / l;
#pragma unroll
    for (int c = 0; c < 4; ++c) {
      float v = ctx[c][reg];
#pragma unroll
      for (int r = 0; r < 11; ++r) v = fmaf(bt[r], krl[r][c * 16 + col], v);
      size_t oidx = (size_t)(b * 1024 + q0 + row0 + reg) * 512 + h * 64 + c * 16 + col;
      if (f32) ((float*)out)[oidx] = v * inv;
      else ((u16*)out)[oidx] = f2bf(v * inv);
    }
  }
}

// ---------------------------------------------------------------------------
extern "C" void kernel_launch(void* const* d_in, const int* in_sizes, int n_in,
                              void* d_out, int out_size, void* d_ws, size_t ws_size,
                              hipStream_t stream) {
  const void* q = d_in[0];
  const void* k = d_in[1];
  const void* v = d_in[2];
  const int* rpr = (const int*)d_in[3];
  const void* wq = d_in[4];
  const void* bq = d_in[5];
  const void* wk = d_in[6];
  const void* bk = d_in[7];
  const void* wv = d_in[8];
  const void* bv = d_in[9];
  const void* krpr = d_in[10];

  int* flag = (int*)d_ws;
  u16* ws = (u16*)((char*)d_ws + 1024);  // bf16 ws: 12.6 MB (validated r10)

  // Host-side dtype from in_sizes[0] when it matches a known BYTE size;
  // otherwise fall back to the validated detect kernel (r24, zero-risk).
  int hflag = -1;
  if (in_sizes && n_in > 0) {
    if (in_sizes[0] == 4194304) hflag = 0;        // bf16 input
    else if (in_sizes[0] == 8388608) hflag = 1;   // f32 input
  }
  if (hflag < 0)
    rpr_detect_kernel<<<1, 256, 0, stream>>>((const u16*)q, flag);

  rpr_proj_mfma<u16><<<dim3(8, 64, 3), 256, 0, stream>>>(
      q, k, v, wq, wk, wv, bq, bk, bv, ws, flag, hflag);
  rpr_attn_mfma<u16><<<dim3(16, 32), 256, 0, stream>>>(
      ws, rpr, krpr, d_out, flag, hflag);
}

// Round 15
// 180.796 us; speedup vs baseline: 1.0327x; 1.0327x over previous
//
#include <hip/hip_runtime.h>

typedef unsigned short u16;
typedef unsigned int u32;
typedef __attribute__((ext_vector_type(8))) short short8;  // 8 bf16 (4 VGPRs)
typedef __attribute__((ext_vector_type(4))) float f32x4;   // MFMA acc
typedef _Float16 f16x2 __attribute__((ext_vector_type(2)));

// ---- bf16 helpers ----
__device__ __forceinline__ float bf2f(u16 v) {
  return __uint_as_float(((u32)v) << 16);
}
__device__ __forceinline__ u16 f2bf(float f) {
  u32 u = __float_as_uint(f);
  return (u16)((u + 0x7fffu + ((u >> 16) & 1u)) >> 16);  // RNE
}
__device__ __forceinline__ u32 pk2(float lo, float hi) {
  return (u32)f2bf(lo) | ((u32)f2bf(hi) << 16);
}

// flagged input loads (fp32 vs bf16, wave-uniform branch)
__device__ __forceinline__ float ld1in(const void* p, size_t i, bool f32) {
  return f32 ? ((const float*)p)[i] : bf2f(((const u16*)p)[i]);
}
__device__ __forceinline__ float4 ld4in(const void* p, size_t i, bool f32) {
  if (f32) return *(const float4*)((const float*)p + i);
  ushort4 u = *(const ushort4*)((const u16*)p + i);
  return make_float4(bf2f(u.x), bf2f(u.y), bf2f(u.z), bf2f(u.w));
}

// ws loads (ws is bf16 — forced since round 10)
__device__ __forceinline__ uint4 ld8ws_pk(const u16* p, size_t i) {
  return *(const uint4*)(p + i);
}

// B=4, S=1024, H=8, DH=64, D=512, NUM_RPR=11
// ws: [int flag][pad->1024B][qh|kh|vh] bf16, each [B*H=32][S=1024][64]
// BANKED LESSONS: (r6/7) no LDS float atomics (NaN). (r8) 128x128 proj tile
// neutral-to-worse. (r9) K/V dbuf + rid-from-global. (r10) bf16 ws. (r13)
// fdot2-bins + packed-P + exp2-fold + no C->D barrier: 73.7->60.0us. (r14/15)
// 8-wave IN-BLOCK k-split DEAD END; launch_bounds 2nd arg = WG/CU VGPR cap.
// (r16) LDS slack useless: occupancy GRID-capped at 2 blocks/CU; grid 512 vs
// 3-block capacity 768 is indivisible without restaging taxes. (r18) conflicts
// (4472832, invariant) live in the qrpr gather; attn floor 59.4us. (r22) rid
// prefetch -6%. (r23) cross-block KV-split: 1024 blocks > 768 capacity ->
// straggler tail, +37us. (r25) swapped-QK^T (P-in-regs): conflicts UP to
// 6.46M (new V-permute + binT collisions), VGPR 68, attn 67.7us — REVERTED.
// ATTN IS CLOSED at the r18 structure: 7 structural attempts, all <= neutral.
// This file = r24 exact (r18 attn + host-side dtype w/ detect fallback),
// the best-validated configuration (~180-183us total, noise band).

// ---------------------------------------------------------------------------
// Kernel 0: dtype detector (fallback only; validated r14/r15).
// ---------------------------------------------------------------------------
__global__ void rpr_detect_kernel(const u16* __restrict__ q, int* __restrict__ flag) {
  __shared__ int cnt4[4];
  int t = threadIdx.x, c = 0;
  for (int i = t; i < 8192; i += 256) {
    unsigned e = (q[i] >> 7) & 0xff;
    c += (e >= 0xC0) ? 1 : 0;
  }
#pragma unroll
  for (int off = 1; off < 64; off <<= 1) c += __shfl_xor(c, off);
  if ((t & 63) == 0) cnt4[t >> 6] = c;
  __syncthreads();
  if (t == 0) *flag = (cnt4[0] + cnt4[1] + cnt4[2] + cnt4[3] > 128) ? 1 : 0;
}

// ---------------------------------------------------------------------------
// Kernel 1: QKV projection via bf16 MFMA, 64x64 tile, BK=32.
// r13-validated dbuf version + hflag (host dtype when known).
// ---------------------------------------------------------------------------
template <typename WT>
__global__ __launch_bounds__(256, 2) void rpr_proj_mfma(
    const void* __restrict__ xq, const void* __restrict__ xk, const void* __restrict__ xv,
    const void* __restrict__ wqp, const void* __restrict__ wkp, const void* __restrict__ wvp,
    const void* __restrict__ bqp, const void* __restrict__ bkp, const void* __restrict__ bvp,
    WT* __restrict__ ws, const int* __restrict__ flagp, int hflag) {
  const bool f32 = (hflag >= 0) ? (hflag != 0) : (*flagp != 0);
  const int z = blockIdx.z;
  const void* __restrict__ X = (z == 0) ? xq : (z == 1) ? xk : xv;
  const void* __restrict__ W = (z == 0) ? wqp : (z == 1) ? wkp : wvp;
  const void* __restrict__ Bb = (z == 0) ? bqp : (z == 1) ? bkp : bvp;
  WT* __restrict__ O = ws + (size_t)z * (4096u * 512u);

  __shared__ u32 as32[2][64][20];  // A[m][k] bf16 u32-paired, dbuf
  __shared__ u32 bs32[2][64][20];  // B^T[n][k] bf16 u32-paired, dbuf

  const int t = threadIdx.x;
  const int wvi = t >> 6, lane = t & 63;
  const int quad = lane >> 4, col = lane & 15;
  const int m0 = blockIdx.y * 64, n0 = blockIdx.x * 64;
  const int am = t >> 2, akc = t & 3;          // A map: row, k-chunk of 8
  const int bkx = t & 15, bnx = (t >> 4) * 4;  // B map: k-pair, n-group of 4

  f32x4 acc[4] = {{0.f, 0.f, 0.f, 0.f}, {0.f, 0.f, 0.f, 0.f},
                  {0.f, 0.f, 0.f, 0.f}, {0.f, 0.f, 0.f, 0.f}};

  // tile loaders: global k0-slice -> registers (uniform dtype branch)
  auto loadA = [&](int k0, uint4& ra) {
    if (!f32) {
      ra = *(const uint4*)((const u16*)X + (size_t)(m0 + am) * 512 + k0 + akc * 8);
    } else {
      const float* xf = (const float*)X + (size_t)(m0 + am) * 512 + k0 + akc * 8;
      float4 a = *(const float4*)xf, b = *(const float4*)(xf + 4);
      ra.x = pk2(a.x, a.y); ra.y = pk2(a.z, a.w);
      ra.z = pk2(b.x, b.y); ra.w = pk2(b.z, b.w);
    }
  };
  auto loadB = [&](int k0, uint4& rb) {
    if (!f32) {
      const u16* w0 = (const u16*)W + (size_t)(k0 + 2 * bkx) * 512 + n0 + bnx;
      ushort4 r0 = *(const ushort4*)w0;
      ushort4 r1 = *(const ushort4*)(w0 + 512);
      rb.x = (u32)r0.x | ((u32)r1.x << 16);
      rb.y = (u32)r0.y | ((u32)r1.y << 16);
      rb.z = (u32)r0.z | ((u32)r1.z << 16);
      rb.w = (u32)r0.w | ((u32)r1.w << 16);
    } else {
      float4 r0 = ld4in(W, (size_t)(k0 + 2 * bkx) * 512 + n0 + bnx, true);
      float4 r1 = ld4in(W, (size_t)(k0 + 2 * bkx + 1) * 512 + n0 + bnx, true);
      rb.x = pk2(r0.x, r1.x);
      rb.y = pk2(r0.y, r1.y);
      rb.z = pk2(r0.z, r1.z);
      rb.w = pk2(r0.w, r1.w);
    }
  };

  // preload tile 0 -> buffer 0
  {
    uint4 ra, rb;
    loadA(0, ra);
    loadB(0, rb);
    *(uint4*)&as32[0][am][akc * 4] = ra;
    bs32[0][bnx + 0][bkx] = rb.x;
    bs32[0][bnx + 1][bkx] = rb.y;
    bs32[0][bnx + 2][bkx] = rb.z;
    bs32[0][bnx + 3][bkx] = rb.w;
  }
  __syncthreads();

  for (int it = 0; it < 16; ++it) {
    const int cur = it & 1;
    // prefetch next tile into registers (hidden under MFMA below)
    uint4 ra, rb;
    if (it < 15) {
      loadA((it + 1) * 32, ra);
      loadB((it + 1) * 32, rb);
    }
    // A-frag: A[m=lane&15][k=quad*8+j]
    short8 aF = *(const short8*)((const u16*)&as32[cur][wvi * 16 + col][0] + quad * 8);
#pragma unroll
    for (int c = 0; c < 4; ++c) {
      // B-frag: B[k=quad*8+j][n=lane&15] read from B^T row n
      short8 bF = *(const short8*)((const u16*)&bs32[cur][c * 16 + col][0] + quad * 8);
      acc[c] = __builtin_amdgcn_mfma_f32_16x16x32_bf16(aF, bF, acc[c], 0, 0, 0);
    }
    // write prefetched tile into the alternate buffer
    if (it < 15) {
      *(uint4*)&as32[1 - cur][am][akc * 4] = ra;
      bs32[1 - cur][bnx + 0][bkx] = rb.x;
      bs32[1 - cur][bnx + 1][bkx] = rb.y;
      bs32[1 - cur][bnx + 2][bkx] = rb.z;
      bs32[1 - cur][bnx + 3][bkx] = rb.w;
    }
    __syncthreads();  // alt buffer visible; cur reads done before next overwrite
  }

  const int h = blockIdx.x;  // n0 >> 6
#pragma unroll
  for (int c = 0; c < 4; ++c) {
    float bias = ld1in(Bb, (size_t)(n0 + c * 16 + col), f32);
#pragma unroll
    for (int reg = 0; reg < 4; ++reg) {
      int m = m0 + wvi * 16 + quad * 4 + reg;  // C layout: row = quad*4+reg
      int bb = m >> 10, s = m & 1023;
      O[((size_t)((bb * 8 + h) * 1024 + s)) * 64 + c * 16 + col] =
          f2bf(acc[c][reg] + bias);
    }
  }
}

// ---------------------------------------------------------------------------
// Kernel 2: MFMA flash attention with RPR — exact r18 green kernel (59.4us)
// + hflag. r18 = r13 structure + ps/qs overlay + chunk swizzle + l-from-bins.
// Swizzle: physical 16B-chunk = (logical + 2*row) mod 8, rows of 8 chunks.
// ---------------------------------------------------------------------------
template <typename WT>
__global__ __launch_bounds__(256, 2) void rpr_attn_mfma(
    const WT* __restrict__ qkv, const int* __restrict__ rpr,
    const void* __restrict__ krpr, void* __restrict__ out,
    const int* __restrict__ flagp, int hflag) {
  const bool f32 = (hflag >= 0) ? (hflag != 0) : (*flagp != 0);
  const int bh = blockIdx.y, q0 = blockIdx.x * 64;
  const int b = bh >> 3, h = bh & 7;
  const WT* __restrict__ qh = qkv + (size_t)bh * 65536;
  const WT* __restrict__ kh = qkv + (size_t)(32 + bh) * 65536;
  const WT* __restrict__ vh = qkv + (size_t)(64 + bh) * 65536;

  __shared__ alignas(16) u16 qps[64][72];  // Q rows (prologue) THEN ps overlay
  __shared__ u16 ks[2][64][72];    // K-tile [key][d], dbuf, chunk-rotated
  __shared__ u32 vs32[2][64][36];  // V^T [d][k'-pair] u32, dbuf, chunk-rotated
  __shared__ float krl[11][64];    // krpr fp32 (unscaled — value-side epilogue)
  __shared__ float qrpr[64][12];   // (q.krpr[r])*0.125*log2e (pre-scaled)
  // total 51968 B (grid-capped at 2 blocks/CU anyway)

  const int t = threadIdx.x;
  const int wvi = t >> 6, lane = t & 63;
  const int quad = lane >> 4, col = lane & 15;
  const int sr = t >> 2, sc4 = (t & 3) * 16;  // Q/K staging: logical cols
  const int kp = t & 31, dg = (t >> 5) * 8;   // V staging map
  // K staging physical col (chunk rotation by 2*row): first uint4 chunk
  const int swk = (((t & 3) + sr) & 3) * 16;  // = phys chunk*8 u16
  // frag-read physical offsets (lane-constant): rot = 2*(row&3) = 2*(col&3)
  const int fo0 = ((quad + 2 * (col & 3)) & 7) * 8;  // u16 off, frag0
  const int fo1 = fo0 ^ 32;                          // frag1 (chunk+4)
  const int vq = kp >> 2, vr = kp & 3;  // V write: u32 slot decomposition

  u16* __restrict__ psw = &qps[0][0] + wvi * (16 * 72);  // per-wave P tile
  const int row0 = wvi * 16 + quad * 4;  // this thread's 4 q-rows base

  // ---- one-time staging (krl, Q, K/V tile 0 -> buffer 0) ----
  for (int i = t; i < 704; i += 256)
    krl[i >> 6][i & 63] = f32 ? ((const float*)krpr)[i] : bf2f(((const u16*)krpr)[i]);
  {
    size_t base = (size_t)(q0 + sr) * 64 + sc4;
    *(uint4*)&qps[sr][sc4] = ld8ws_pk(qh, base);
    *(uint4*)&qps[sr][sc4 + 8] = ld8ws_pk(qh, base + 8);
  }
  {
    size_t kb = (size_t)sr * 64 + sc4;
    *(uint4*)&ks[0][sr][swk] = ld8ws_pk(kh, kb);
    *(uint4*)&ks[0][sr][swk + 8] = ld8ws_pk(kh, kb + 8);
    size_t vb = (size_t)(2 * kp) * 64 + dg;
    uint4 va = ld8ws_pk(vh, vb), vbb = ld8ws_pk(vh, vb + 64);
    vs32[0][dg + 0][((vq + 0) & 7) * 4 + vr] = (va.x & 0xffffu) | (vbb.x << 16);
    vs32[0][dg + 1][((vq + 2) & 7) * 4 + vr] = (va.x >> 16) | (vbb.x & 0xffff0000u);
    vs32[0][dg + 2][((vq + 4) & 7) * 4 + vr] = (va.y & 0xffffu) | (vbb.y << 16);
    vs32[0][dg + 3][((vq + 6) & 7) * 4 + vr] = (va.y >> 16) | (vbb.y & 0xffff0000u);
    vs32[0][dg + 4][((vq + 0) & 7) * 4 + vr] = (va.z & 0xffffu) | (vbb.z << 16);
    vs32[0][dg + 5][((vq + 2) & 7) * 4 + vr] = (va.z >> 16) | (vbb.z & 0xffff0000u);
    vs32[0][dg + 6][((vq + 4) & 7) * 4 + vr] = (va.w & 0xffffu) | (vbb.w << 16);
    vs32[0][dg + 7][((vq + 6) & 7) * 4 + vr] = (va.w >> 16) | (vbb.w & 0xffff0000u);
  }
  __syncthreads();
  // qrpr[row][r]: thread -> row t>>2, r in {t&3, +4, +8}; pre-scaled by 0.125*log2e
  {
    const float SC = 0.18033688011112042f;  // 0.125 * log2(e)
    int r = t >> 2, rb = t & 3;
    float d0 = 0.f, d1 = 0.f, d2 = 0.f;
    for (int d = 0; d < 64; ++d) {
      float qv = bf2f(qps[r][d]);
      d0 = fmaf(qv, krl[rb][d], d0);
      d1 = fmaf(qv, krl[rb + 4][d], d1);
      if (rb < 3) d2 = fmaf(qv, krl[rb + 8][d], d2);
    }
    qrpr[r][rb] = d0 * SC;
    qrpr[r][rb + 4] = d1 * SC;
    if (rb < 3) qrpr[r][rb + 8] = d2 * SC;
  }
  // Q A-frags: A[m=lane&15][k=quad*8+j], two k-halves of DH=64 (unswizzled)
  short8 qA0, qA1;
  {
    const u16* qrow = &qps[wvi * 16 + col][0];
    qA0 = *(const short8*)(qrow + quad * 8);
    qA1 = *(const short8*)(qrow + 32 + quad * 8);
  }
  __syncthreads();  // qrpr + frags consumed; qps region becomes ps from here

  float bins[4][11] = {};  // registers (LDS atomics are poison — rounds 6/7)
  f32x4 ctx[4] = {{0.f, 0.f, 0.f, 0.f}, {0.f, 0.f, 0.f, 0.f},
                  {0.f, 0.f, 0.f, 0.f}, {0.f, 0.f, 0.f, 0.f}};

  for (int kt = 0; kt < 16; ++kt) {
    const int cur = kt & 1;
    // (A) prefetch next K/V tile into registers (latency hidden under B-E)
    uint4 pk0, pk1, pva, pvb;
    if (kt < 15) {
      size_t kb = (size_t)((kt + 1) * 64 + sr) * 64 + sc4;
      pk0 = ld8ws_pk(kh, kb);
      pk1 = ld8ws_pk(kh, kb + 8);
      size_t vb = (size_t)((kt + 1) * 64 + 2 * kp) * 64 + dg;
      pva = ld8ws_pk(vh, vb);
      pvb = ld8ws_pk(vh, vb + 64);
    }
    // rid direct from global (L2-hot; validated round 9; r22 prefetch -6%)
    int rid[4][4];
    {
      const int* rbase = rpr + (size_t)(q0 + row0) * 1024 + kt * 64 + col;
#pragma unroll
      for (int reg = 0; reg < 4; ++reg)
#pragma unroll
        for (int c = 0; c < 4; ++c) rid[c][reg] = rbase[reg * 1024 + c * 16];
    }
    // (B) scores: QK^T via MFMA, 4 chunks of 16 keys (swizzled frag reads)
    f32x4 sc[4];
#pragma unroll
    for (int c = 0; c < 4; ++c) {
      const u16* kb = &ks[cur][c * 16 + col][0];
      short8 kB0 = *(const short8*)(kb + fo0);
      short8 kB1 = *(const short8*)(kb + fo1);
      f32x4 a = {0.f, 0.f, 0.f, 0.f};
      a = __builtin_amdgcn_mfma_f32_16x16x32_bf16(qA0, kB0, a, 0, 0, 0);
      a = __builtin_amdgcn_mfma_f32_16x16x32_bf16(qA1, kB1, a, 0, 0, 0);
      sc[c] = a;
    }
    // (C) p = exp2(fma(s, SC, qrpr[row][rid])); bins via packed-f16 fdot2;
    //     P written as packed bf16 pairs at k' = col*4 + c
#pragma unroll
    for (int reg = 0; reg < 4; ++reg) {
      const int row = row0 + reg;  // C layout: row = quad*4+reg
      float p4[4];
#pragma unroll
      for (int c = 0; c < 4; ++c) {
        float x = fmaf(sc[c][reg], 0.18033688011112042f, qrpr[row][rid[c][reg]]);
        float pe;
        asm("v_exp_f32 %0, %1" : "=v"(pe) : "v"(x));  // exp2: scales pre-folded
        p4[c] = pe;
      }
      f16x2 ph01 = __builtin_bit_cast(f16x2, __builtin_amdgcn_cvt_pkrtz(p4[0], p4[1]));
      f16x2 ph23 = __builtin_bit_cast(f16x2, __builtin_amdgcn_cvt_pkrtz(p4[2], p4[3]));
      u32 m01 = (1u << (u32)rid[0][reg]) | (0x10000u << (u32)rid[1][reg]);
      u32 m23 = (1u << (u32)rid[2][reg]) | (0x10000u << (u32)rid[3][reg]);
#pragma unroll
      for (int r = 0; r < 11; ++r) {
        // ((m>>r)&0x10001)*0x3C00 -> exact packed-f16 {1.0|0, 1.0|0} selector
        u32 s01 = ((m01 >> r) & 0x00010001u) * 0x3C00u;
        u32 s23 = ((m23 >> r) & 0x00010001u) * 0x3C00u;
        bins[reg][r] = __builtin_amdgcn_fdot2(ph01, __builtin_bit_cast(f16x2, s01),
                                              bins[reg][r], false);
        bins[reg][r] = __builtin_amdgcn_fdot2(ph23, __builtin_bit_cast(f16x2, s23),
                                              bins[reg][r], false);
      }
      u32 plo, phi;
      asm("v_cvt_pk_bf16_f32 %0, %1, %2" : "=v"(plo) : "v"(p4[0]), "v"(p4[1]));
      asm("v_cvt_pk_bf16_f32 %0, %1, %2" : "=v"(phi) : "v"(p4[2]), "v"(p4[3]));
      *(uint2*)(psw + (quad * 4 + reg) * 72 + col * 4) = make_uint2(plo, phi);
    }
    // no barrier: psw is wave-private; lgkmcnt orders ds_write->ds_read (r13)

    // (D) PV: P (A-layout, k'-ordered) x V^T rows (B-layout, swizzled reads)
    short8 pA0, pA1;
    {
      const u16* prow = psw + col * 72;
      pA0 = *(const short8*)(prow + quad * 8);
      pA1 = *(const short8*)(prow + 32 + quad * 8);
    }
#pragma unroll
    for (int c = 0; c < 4; ++c) {
      const u16* vrow = (const u16*)&vs32[cur][c * 16 + col][0];
      short8 vB0 = *(const short8*)(vrow + fo0);
      short8 vB1 = *(const short8*)(vrow + fo1);
      ctx[c] = __builtin_amdgcn_mfma_f32_16x16x32_bf16(pA0, vB0, ctx[c], 0, 0, 0);
      ctx[c] = __builtin_amdgcn_mfma_f32_16x16x32_bf16(pA1, vB1, ctx[c], 0, 0, 0);
    }
    // (E) write prefetched tile into the alternate buffer (rotated chunks)
    if (kt < 15) {
      *(uint4*)&ks[1 - cur][sr][swk] = pk0;
      *(uint4*)&ks[1 - cur][sr][swk + 8] = pk1;
      vs32[1 - cur][dg + 0][((vq + 0) & 7) * 4 + vr] = (pva.x & 0xffffu) | (pvb.x << 16);
      vs32[1 - cur][dg + 1][((vq + 2) & 7) * 4 + vr] = (pva.x >> 16) | (pvb.x & 0xffff0000u);
      vs32[1 - cur][dg + 2][((vq + 4) & 7) * 4 + vr] = (pva.y & 0xffffu) | (pvb.y << 16);
      vs32[1 - cur][dg + 3][((vq + 6) & 7) * 4 + vr] = (pva.y >> 16) | (pvb.y & 0xffff0000u);
      vs32[1 - cur][dg + 4][((vq + 0) & 7) * 4 + vr] = (pva.z & 0xffffu) | (pvb.z << 16);
      vs32[1 - cur][dg + 5][((vq + 2) & 7) * 4 + vr] = (pva.z >> 16) | (pvb.z & 0xffff0000u);
      vs32[1 - cur][dg + 6][((vq + 4) & 7) * 4 + vr] = (pva.w & 0xffffu) | (pvb.w << 16);
      vs32[1 - cur][dg + 7][((vq + 6) & 7) * 4 + vr] = (pva.w >> 16) | (pvb.w & 0xffff0000u);
    }
    __syncthreads();  // next tile's frag reads see the new buffer
  }

  // ---- epilogue: reduce bins over 16 lanes of each quad; l = sum_r bins ----
#pragma unroll
  for (int off = 1; off < 16; off <<= 1) {
#pragma unroll
    for (int reg = 0; reg < 4; ++reg) {
#pragma unroll
      for (int r = 0; r < 11; ++r) bins[reg][r] += __shfl_xor(bins[reg][r], off);
    }
  }
  // value-side RPR + normalize + store
#pragma unroll
  for (int reg = 0; reg < 4; ++reg) {
    int row = row0 + reg;
    float l = bins[reg][0];
#pragma unroll
    for (int r = 1; r < 11; ++r) l += bins[reg][r];
    float inv = 1.f / l;
#pragma unroll
    for (int c = 0; c < 4; ++c) {
      float v = ctx[c][reg];
#pragma unroll
      for (int r = 0; r < 11; ++r) v = fmaf(bins[reg][r], krl[r][c * 16 + col], v);
      size_t oidx = (size_t)(b * 1024 + q0 + row) * 512 + h * 64 + c * 16 + col;
      if (f32) ((float*)out)[oidx] = v * inv;
      else ((u16*)out)[oidx] = f2bf(v * inv);
    }
  }
}

// ---------------------------------------------------------------------------
extern "C" void kernel_launch(void* const* d_in, const int* in_sizes, int n_in,
                              void* d_out, int out_size, void* d_ws, size_t ws_size,
                              hipStream_t stream) {
  const void* q = d_in[0];
  const void* k = d_in[1];
  const void* v = d_in[2];
  const int* rpr = (const int*)d_in[3];
  const void* wq = d_in[4];
  const void* bq = d_in[5];
  const void* wk = d_in[6];
  const void* bk = d_in[7];
  const void* wv = d_in[8];
  const void* bv = d_in[9];
  const void* krpr = d_in[10];

  int* flag = (int*)d_ws;
  u16* ws = (u16*)((char*)d_ws + 1024);  // bf16 ws: 12.6 MB (validated r10)

  // Host-side dtype: q is B*S*D = 2,097,152 elements. If in_sizes[0] is a
  // byte count it is 4194304 (bf16) or 8388608 (f32) — decisive. Any other
  // value (e.g. an element-count convention) -> fall back to detect kernel.
  int hflag = -1;
  if (in_sizes && n_in > 0) {
    if (in_sizes[0] == 4194304) hflag = 0;        // bf16 input
    else if (in_sizes[0] == 8388608) hflag = 1;   // f32 input
  }
  if (hflag < 0)
    rpr_detect_kernel<<<1, 256, 0, stream>>>((const u16*)q, flag);

  rpr_proj_mfma<u16><<<dim3(8, 64, 3), 256, 0, stream>>>(
      q, k, v, wq, wk, wv, bq, bk, bv, ws, flag, hflag);
  rpr_attn_mfma<u16><<<dim3(16, 32), 256, 0, stream>>>(
      ws, rpr, krpr, d_out, flag, hflag);
}

// Round 16
// 177.266 us; speedup vs baseline: 1.0532x; 1.0199x over previous
//
#include <hip/hip_runtime.h>

typedef unsigned short u16;
typedef unsigned int u32;
typedef __attribute__((ext_vector_type(8))) short short8;  // 8 bf16 (4 VGPRs)
typedef __attribute__((ext_vector_type(4))) float f32x4;   // MFMA acc
typedef _Float16 f16x2 __attribute__((ext_vector_type(2)));

// ---- bf16 helpers ----
__device__ __forceinline__ float bf2f(u16 v) {
  return __uint_as_float(((u32)v) << 16);
}
__device__ __forceinline__ u16 f2bf(float f) {
  u32 u = __float_as_uint(f);
  return (u16)((u + 0x7fffu + ((u >> 16) & 1u)) >> 16);  // RNE
}
__device__ __forceinline__ u32 pk2(float lo, float hi) {
  return (u32)f2bf(lo) | ((u32)f2bf(hi) << 16);
}

// flagged input loads (fp32 vs bf16, wave-uniform branch)
__device__ __forceinline__ float ld1in(const void* p, size_t i, bool f32) {
  return f32 ? ((const float*)p)[i] : bf2f(((const u16*)p)[i]);
}
__device__ __forceinline__ float4 ld4in(const void* p, size_t i, bool f32) {
  if (f32) return *(const float4*)((const float*)p + i);
  ushort4 u = *(const ushort4*)((const u16*)p + i);
  return make_float4(bf2f(u.x), bf2f(u.y), bf2f(u.z), bf2f(u.w));
}

// ws loads (ws is bf16 — forced since round 10)
__device__ __forceinline__ uint4 ld8ws_pk(const u16* p, size_t i) {
  return *(const uint4*)(p + i);
}

// B=4, S=1024, H=8, DH=64, D=512, NUM_RPR=11
// ws: [int flag][pad->1024B][qh|kh|vh] bf16, each [B*H=32][S=1024][64]
// BANKED LESSONS: (r6/7) no LDS float atomics (NaN). (r8) 128x128 proj tile
// neutral-to-worse. (r9) K/V dbuf + rid-from-global. (r10) bf16 ws. (r13)
// fdot2-bins + packed-P + exp2-fold + no C->D barrier: 73.7->60.0us. (r14/15)
// 8-wave IN-BLOCK k-split DEAD END; launch_bounds 2nd arg = WG/CU VGPR cap.
// (r16) LDS slack useless: occupancy GRID-capped at 2 blocks/CU. (r18)
// conflicts (4472832, invariant) live in the qrpr gather; attn floor 59.4us.
// (r22) rid prefetch -6%. (r23) cross-block KV-split +37us. (r25) swapped-
// QK^T (P-in-regs): conflicts UP (6.46M), attn 67.7us — reverted. ATTN CLOSED
// at r18 structure (7 structural attempts, all <= neutral). ACCOUNTING:
// total - attn == 120 +/- 1.5us across ALL green rounds; proj < 61us (never
// in top-5), est. 20-40us from m90-class rate -> ~50-90us is launch/serial
// overhead of the 3-deep chain.
// ROUND 27: DELETE the detect launch. Each proj block runs the identical
// 8192-sample detect locally on q (parallel, L2-hot, ~0 wall cost); proj
// block (0,0,0) writes the flag for attn (single writer, visible at kernel
// boundary — same mechanism as the old detect->proj handoff). Launch chain
// 3 -> 2. hflag fast path kept. This is also the decomposition probe: total
// flat => ~120us is proj + fixed harness cost (practical floor).

// ---------------------------------------------------------------------------
// Kernel 1: QKV projection via bf16 MFMA, 64x64 tile, BK=32.
// r13-validated dbuf core + integrated local dtype detect (r27).
// ---------------------------------------------------------------------------
template <typename WT>
__global__ __launch_bounds__(256, 2) void rpr_proj_mfma(
    const void* __restrict__ xq, const void* __restrict__ xk, const void* __restrict__ xv,
    const void* __restrict__ wqp, const void* __restrict__ wkp, const void* __restrict__ wvp,
    const void* __restrict__ bqp, const void* __restrict__ bkp, const void* __restrict__ bvp,
    WT* __restrict__ ws, int* __restrict__ flagp, int hflag) {
  const int t = threadIdx.x;

  // ---- local dtype detect (identical 8192-sample logic; q sampled by ALL
  // blocks — same result everywhere). Block (0,0,0) publishes for attn. ----
  __shared__ int dcnt[4];
  bool f32;
  if (hflag >= 0) {
    f32 = (hflag != 0);
  } else {
    const u16* qd = (const u16*)xq;
    int c = 0;
    for (int i = t; i < 8192; i += 256) {
      unsigned e = (qd[i] >> 7) & 0xff;
      c += (e >= 0xC0) ? 1 : 0;
    }
#pragma unroll
    for (int off = 1; off < 64; off <<= 1) c += __shfl_xor(c, off);
    if ((t & 63) == 0) dcnt[t >> 6] = c;
    __syncthreads();
    f32 = (dcnt[0] + dcnt[1] + dcnt[2] + dcnt[3] > 128);
    if (blockIdx.x == 0 && blockIdx.y == 0 && blockIdx.z == 0 && t == 0)
      *flagp = f32 ? 1 : 0;
  }

  const int z = blockIdx.z;
  const void* __restrict__ X = (z == 0) ? xq : (z == 1) ? xk : xv;
  const void* __restrict__ W = (z == 0) ? wqp : (z == 1) ? wkp : wvp;
  const void* __restrict__ Bb = (z == 0) ? bqp : (z == 1) ? bkp : bvp;
  WT* __restrict__ O = ws + (size_t)z * (4096u * 512u);

  __shared__ u32 as32[2][64][20];  // A[m][k] bf16 u32-paired, dbuf
  __shared__ u32 bs32[2][64][20];  // B^T[n][k] bf16 u32-paired, dbuf

  const int wvi = t >> 6, lane = t & 63;
  const int quad = lane >> 4, col = lane & 15;
  const int m0 = blockIdx.y * 64, n0 = blockIdx.x * 64;
  const int am = t >> 2, akc = t & 3;          // A map: row, k-chunk of 8
  const int bkx = t & 15, bnx = (t >> 4) * 4;  // B map: k-pair, n-group of 4

  f32x4 acc[4] = {{0.f, 0.f, 0.f, 0.f}, {0.f, 0.f, 0.f, 0.f},
                  {0.f, 0.f, 0.f, 0.f}, {0.f, 0.f, 0.f, 0.f}};

  // tile loaders: global k0-slice -> registers (uniform dtype branch)
  auto loadA = [&](int k0, uint4& ra) {
    if (!f32) {
      ra = *(const uint4*)((const u16*)X + (size_t)(m0 + am) * 512 + k0 + akc * 8);
    } else {
      const float* xf = (const float*)X + (size_t)(m0 + am) * 512 + k0 + akc * 8;
      float4 a = *(const float4*)xf, b = *(const float4*)(xf + 4);
      ra.x = pk2(a.x, a.y); ra.y = pk2(a.z, a.w);
      ra.z = pk2(b.x, b.y); ra.w = pk2(b.z, b.w);
    }
  };
  auto loadB = [&](int k0, uint4& rb) {
    if (!f32) {
      const u16* w0 = (const u16*)W + (size_t)(k0 + 2 * bkx) * 512 + n0 + bnx;
      ushort4 r0 = *(const ushort4*)w0;
      ushort4 r1 = *(const ushort4*)(w0 + 512);
      rb.x = (u32)r0.x | ((u32)r1.x << 16);
      rb.y = (u32)r0.y | ((u32)r1.y << 16);
      rb.z = (u32)r0.z | ((u32)r1.z << 16);
      rb.w = (u32)r0.w | ((u32)r1.w << 16);
    } else {
      float4 r0 = ld4in(W, (size_t)(k0 + 2 * bkx) * 512 + n0 + bnx, true);
      float4 r1 = ld4in(W, (size_t)(k0 + 2 * bkx + 1) * 512 + n0 + bnx, true);
      rb.x = pk2(r0.x, r1.x);
      rb.y = pk2(r0.y, r1.y);
      rb.z = pk2(r0.z, r1.z);
      rb.w = pk2(r0.w, r1.w);
    }
  };

  // preload tile 0 -> buffer 0
  {
    uint4 ra, rb;
    loadA(0, ra);
    loadB(0, rb);
    *(uint4*)&as32[0][am][akc * 4] = ra;
    bs32[0][bnx + 0][bkx] = rb.x;
    bs32[0][bnx + 1][bkx] = rb.y;
    bs32[0][bnx + 2][bkx] = rb.z;
    bs32[0][bnx + 3][bkx] = rb.w;
  }
  __syncthreads();

  for (int it = 0; it < 16; ++it) {
    const int cur = it & 1;
    // prefetch next tile into registers (hidden under MFMA below)
    uint4 ra, rb;
    if (it < 15) {
      loadA((it + 1) * 32, ra);
      loadB((it + 1) * 32, rb);
    }
    // A-frag: A[m=lane&15][k=quad*8+j]
    short8 aF = *(const short8*)((const u16*)&as32[cur][wvi * 16 + col][0] + quad * 8);
#pragma unroll
    for (int c = 0; c < 4; ++c) {
      // B-frag: B[k=quad*8+j][n=lane&15] read from B^T row n
      short8 bF = *(const short8*)((const u16*)&bs32[cur][c * 16 + col][0] + quad * 8);
      acc[c] = __builtin_amdgcn_mfma_f32_16x16x32_bf16(aF, bF, acc[c], 0, 0, 0);
    }
    // write prefetched tile into the alternate buffer
    if (it < 15) {
      *(uint4*)&as32[1 - cur][am][akc * 4] = ra;
      bs32[1 - cur][bnx + 0][bkx] = rb.x;
      bs32[1 - cur][bnx + 1][bkx] = rb.y;
      bs32[1 - cur][bnx + 2][bkx] = rb.z;
      bs32[1 - cur][bnx + 3][bkx] = rb.w;
    }
    __syncthreads();  // alt buffer visible; cur reads done before next overwrite
  }

  const int h = blockIdx.x;  // n0 >> 6
#pragma unroll
  for (int c = 0; c < 4; ++c) {
    float bias = ld1in(Bb, (size_t)(n0 + c * 16 + col), f32);
#pragma unroll
    for (int reg = 0; reg < 4; ++reg) {
      int m = m0 + wvi * 16 + quad * 4 + reg;  // C layout: row = quad*4+reg
      int bb = m >> 10, s = m & 1023;
      O[((size_t)((bb * 8 + h) * 1024 + s)) * 64 + c * 16 + col] =
          f2bf(acc[c][reg] + bias);
    }
  }
}

// ---------------------------------------------------------------------------
// Kernel 2: MFMA flash attention with RPR — exact r18 green kernel (59.4us)
// + hflag. r18 = r13 structure + ps/qs overlay + chunk swizzle + l-from-bins.
// Swizzle: physical 16B-chunk = (logical + 2*row) mod 8, rows of 8 chunks.
// ---------------------------------------------------------------------------
template <typename WT>
__global__ __launch_bounds__(256, 2) void rpr_attn_mfma(
    const WT* __restrict__ qkv, const int* __restrict__ rpr,
    const void* __restrict__ krpr, void* __restrict__ out,
    const int* __restrict__ flagp, int hflag) {
  const bool f32 = (hflag >= 0) ? (hflag != 0) : (*flagp != 0);
  const int bh = blockIdx.y, q0 = blockIdx.x * 64;
  const int b = bh >> 3, h = bh & 7;
  const WT* __restrict__ qh = qkv + (size_t)bh * 65536;
  const WT* __restrict__ kh = qkv + (size_t)(32 + bh) * 65536;
  const WT* __restrict__ vh = qkv + (size_t)(64 + bh) * 65536;

  __shared__ alignas(16) u16 qps[64][72];  // Q rows (prologue) THEN ps overlay
  __shared__ u16 ks[2][64][72];    // K-tile [key][d], dbuf, chunk-rotated
  __shared__ u32 vs32[2][64][36];  // V^T [d][k'-pair] u32, dbuf, chunk-rotated
  __shared__ float krl[11][64];    // krpr fp32 (unscaled — value-side epilogue)
  __shared__ float qrpr[64][12];   // (q.krpr[r])*0.125*log2e (pre-scaled)
  // total 51968 B (grid-capped at 2 blocks/CU anyway)

  const int t = threadIdx.x;
  const int wvi = t >> 6, lane = t & 63;
  const int quad = lane >> 4, col = lane & 15;
  const int sr = t >> 2, sc4 = (t & 3) * 16;  // Q/K staging: logical cols
  const int kp = t & 31, dg = (t >> 5) * 8;   // V staging map
  // K staging physical col (chunk rotation by 2*row): first uint4 chunk
  const int swk = (((t & 3) + sr) & 3) * 16;  // = phys chunk*8 u16
  // frag-read physical offsets (lane-constant): rot = 2*(row&3) = 2*(col&3)
  const int fo0 = ((quad + 2 * (col & 3)) & 7) * 8;  // u16 off, frag0
  const int fo1 = fo0 ^ 32;                          // frag1 (chunk+4)
  const int vq = kp >> 2, vr = kp & 3;  // V write: u32 slot decomposition

  u16* __restrict__ psw = &qps[0][0] + wvi * (16 * 72);  // per-wave P tile
  const int row0 = wvi * 16 + quad * 4;  // this thread's 4 q-rows base

  // ---- one-time staging (krl, Q, K/V tile 0 -> buffer 0) ----
  for (int i = t; i < 704; i += 256)
    krl[i >> 6][i & 63] = f32 ? ((const float*)krpr)[i] : bf2f(((const u16*)krpr)[i]);
  {
    size_t base = (size_t)(q0 + sr) * 64 + sc4;
    *(uint4*)&qps[sr][sc4] = ld8ws_pk(qh, base);
    *(uint4*)&qps[sr][sc4 + 8] = ld8ws_pk(qh, base + 8);
  }
  {
    size_t kb = (size_t)sr * 64 + sc4;
    *(uint4*)&ks[0][sr][swk] = ld8ws_pk(kh, kb);
    *(uint4*)&ks[0][sr][swk + 8] = ld8ws_pk(kh, kb + 8);
    size_t vb = (size_t)(2 * kp) * 64 + dg;
    uint4 va = ld8ws_pk(vh, vb), vbb = ld8ws_pk(vh, vb + 64);
    vs32[0][dg + 0][((vq + 0) & 7) * 4 + vr] = (va.x & 0xffffu) | (vbb.x << 16);
    vs32[0][dg + 1][((vq + 2) & 7) * 4 + vr] = (va.x >> 16) | (vbb.x & 0xffff0000u);
    vs32[0][dg + 2][((vq + 4) & 7) * 4 + vr] = (va.y & 0xffffu) | (vbb.y << 16);
    vs32[0][dg + 3][((vq + 6) & 7) * 4 + vr] = (va.y >> 16) | (vbb.y & 0xffff0000u);
    vs32[0][dg + 4][((vq + 0) & 7) * 4 + vr] = (va.z & 0xffffu) | (vbb.z << 16);
    vs32[0][dg + 5][((vq + 2) & 7) * 4 + vr] = (va.z >> 16) | (vbb.z & 0xffff0000u);
    vs32[0][dg + 6][((vq + 4) & 7) * 4 + vr] = (va.w & 0xffffu) | (vbb.w << 16);
    vs32[0][dg + 7][((vq + 6) & 7) * 4 + vr] = (va.w >> 16) | (vbb.w & 0xffff0000u);
  }
  __syncthreads();
  // qrpr[row][r]: thread -> row t>>2, r in {t&3, +4, +8}; pre-scaled by 0.125*log2e
  {
    const float SC = 0.18033688011112042f;  // 0.125 * log2(e)
    int r = t >> 2, rb = t & 3;
    float d0 = 0.f, d1 = 0.f, d2 = 0.f;
    for (int d = 0; d < 64; ++d) {
      float qv = bf2f(qps[r][d]);
      d0 = fmaf(qv, krl[rb][d], d0);
      d1 = fmaf(qv, krl[rb + 4][d], d1);
      if (rb < 3) d2 = fmaf(qv, krl[rb + 8][d], d2);
    }
    qrpr[r][rb] = d0 * SC;
    qrpr[r][rb + 4] = d1 * SC;
    if (rb < 3) qrpr[r][rb + 8] = d2 * SC;
  }
  // Q A-frags: A[m=lane&15][k=quad*8+j], two k-halves of DH=64 (unswizzled)
  short8 qA0, qA1;
  {
    const u16* qrow = &qps[wvi * 16 + col][0];
    qA0 = *(const short8*)(qrow + quad * 8);
    qA1 = *(const short8*)(qrow + 32 + quad * 8);
  }
  __syncthreads();  // qrpr + frags consumed; qps region becomes ps from here

  float bins[4][11] = {};  // registers (LDS atomics are poison — rounds 6/7)
  f32x4 ctx[4] = {{0.f, 0.f, 0.f, 0.f}, {0.f, 0.f, 0.f, 0.f},
                  {0.f, 0.f, 0.f, 0.f}, {0.f, 0.f, 0.f, 0.f}};

  for (int kt = 0; kt < 16; ++kt) {
    const int cur = kt & 1;
    // (A) prefetch next K/V tile into registers (latency hidden under B-E)
    uint4 pk0, pk1, pva, pvb;
    if (kt < 15) {
      size_t kb = (size_t)((kt + 1) * 64 + sr) * 64 + sc4;
      pk0 = ld8ws_pk(kh, kb);
      pk1 = ld8ws_pk(kh, kb + 8);
      size_t vb = (size_t)((kt + 1) * 64 + 2 * kp) * 64 + dg;
      pva = ld8ws_pk(vh, vb);
      pvb = ld8ws_pk(vh, vb + 64);
    }
    // rid direct from global (L2-hot; validated round 9; r22 prefetch -6%)
    int rid[4][4];
    {
      const int* rbase = rpr + (size_t)(q0 + row0) * 1024 + kt * 64 + col;
#pragma unroll
      for (int reg = 0; reg < 4; ++reg)
#pragma unroll
        for (int c = 0; c < 4; ++c) rid[c][reg] = rbase[reg * 1024 + c * 16];
    }
    // (B) scores: QK^T via MFMA, 4 chunks of 16 keys (swizzled frag reads)
    f32x4 sc[4];
#pragma unroll
    for (int c = 0; c < 4; ++c) {
      const u16* kb = &ks[cur][c * 16 + col][0];
      short8 kB0 = *(const short8*)(kb + fo0);
      short8 kB1 = *(const short8*)(kb + fo1);
      f32x4 a = {0.f, 0.f, 0.f, 0.f};
      a = __builtin_amdgcn_mfma_f32_16x16x32_bf16(qA0, kB0, a, 0, 0, 0);
      a = __builtin_amdgcn_mfma_f32_16x16x32_bf16(qA1, kB1, a, 0, 0, 0);
      sc[c] = a;
    }
    // (C) p = exp2(fma(s, SC, qrpr[row][rid])); bins via packed-f16 fdot2;
    //     P written as packed bf16 pairs at k' = col*4 + c
#pragma unroll
    for (int reg = 0; reg < 4; ++reg) {
      const int row = row0 + reg;  // C layout: row = quad*4+reg
      float p4[4];
#pragma unroll
      for (int c = 0; c < 4; ++c) {
        float x = fmaf(sc[c][reg], 0.18033688011112042f, qrpr[row][rid[c][reg]]);
        float pe;
        asm("v_exp_f32 %0, %1" : "=v"(pe) : "v"(x));  // exp2: scales pre-folded
        p4[c] = pe;
      }
      f16x2 ph01 = __builtin_bit_cast(f16x2, __builtin_amdgcn_cvt_pkrtz(p4[0], p4[1]));
      f16x2 ph23 = __builtin_bit_cast(f16x2, __builtin_amdgcn_cvt_pkrtz(p4[2], p4[3]));
      u32 m01 = (1u << (u32)rid[0][reg]) | (0x10000u << (u32)rid[1][reg]);
      u32 m23 = (1u << (u32)rid[2][reg]) | (0x10000u << (u32)rid[3][reg]);
#pragma unroll
      for (int r = 0; r < 11; ++r) {
        // ((m>>r)&0x10001)*0x3C00 -> exact packed-f16 {1.0|0, 1.0|0} selector
        u32 s01 = ((m01 >> r) & 0x00010001u) * 0x3C00u;
        u32 s23 = ((m23 >> r) & 0x00010001u) * 0x3C00u;
        bins[reg][r] = __builtin_amdgcn_fdot2(ph01, __builtin_bit_cast(f16x2, s01),
                                              bins[reg][r], false);
        bins[reg][r] = __builtin_amdgcn_fdot2(ph23, __builtin_bit_cast(f16x2, s23),
                                              bins[reg][r], false);
      }
      u32 plo, phi;
      asm("v_cvt_pk_bf16_f32 %0, %1, %2" : "=v"(plo) : "v"(p4[0]), "v"(p4[1]));
      asm("v_cvt_pk_bf16_f32 %0, %1, %2" : "=v"(phi) : "v"(p4[2]), "v"(p4[3]));
      *(uint2*)(psw + (quad * 4 + reg) * 72 + col * 4) = make_uint2(plo, phi);
    }
    // no barrier: psw is wave-private; lgkmcnt orders ds_write->ds_read (r13)

    // (D) PV: P (A-layout, k'-ordered) x V^T rows (B-layout, swizzled reads)
    short8 pA0, pA1;
    {
      const u16* prow = psw + col * 72;
      pA0 = *(const short8*)(prow + quad * 8);
      pA1 = *(const short8*)(prow + 32 + quad * 8);
    }
#pragma unroll
    for (int c = 0; c < 4; ++c) {
      const u16* vrow = (const u16*)&vs32[cur][c * 16 + col][0];
      short8 vB0 = *(const short8*)(vrow + fo0);
      short8 vB1 = *(const short8*)(vrow + fo1);
      ctx[c] = __builtin_amdgcn_mfma_f32_16x16x32_bf16(pA0, vB0, ctx[c], 0, 0, 0);
      ctx[c] = __builtin_amdgcn_mfma_f32_16x16x32_bf16(pA1, vB1, ctx[c], 0, 0, 0);
    }
    // (E) write prefetched tile into the alternate buffer (rotated chunks)
    if (kt < 15) {
      *(uint4*)&ks[1 - cur][sr][swk] = pk0;
      *(uint4*)&ks[1 - cur][sr][swk + 8] = pk1;
      vs32[1 - cur][dg + 0][((vq + 0) & 7) * 4 + vr] = (pva.x & 0xffffu) | (pvb.x << 16);
      vs32[1 - cur][dg + 1][((vq + 2) & 7) * 4 + vr] = (pva.x >> 16) | (pvb.x & 0xffff0000u);
      vs32[1 - cur][dg + 2][((vq + 4) & 7) * 4 + vr] = (pva.y & 0xffffu) | (pvb.y << 16);
      vs32[1 - cur][dg + 3][((vq + 6) & 7) * 4 + vr] = (pva.y >> 16) | (pvb.y & 0xffff0000u);
      vs32[1 - cur][dg + 4][((vq + 0) & 7) * 4 + vr] = (pva.z & 0xffffu) | (pvb.z << 16);
      vs32[1 - cur][dg + 5][((vq + 2) & 7) * 4 + vr] = (pva.z >> 16) | (pvb.z & 0xffff0000u);
      vs32[1 - cur][dg + 6][((vq + 4) & 7) * 4 + vr] = (pva.w & 0xffffu) | (pvb.w << 16);
      vs32[1 - cur][dg + 7][((vq + 6) & 7) * 4 + vr] = (pva.w >> 16) | (pvb.w & 0xffff0000u);
    }
    __syncthreads();  // next tile's frag reads see the new buffer
  }

  // ---- epilogue: reduce bins over 16 lanes of each quad; l = sum_r bins ----
#pragma unroll
  for (int off = 1; off < 16; off <<= 1) {
#pragma unroll
    for (int reg = 0; reg < 4; ++reg) {
#pragma unroll
      for (int r = 0; r < 11; ++r) bins[reg][r] += __shfl_xor(bins[reg][r], off);
    }
  }
  // value-side RPR + normalize + store
#pragma unroll
  for (int reg = 0; reg < 4; ++reg) {
    int row = row0 + reg;
    float l = bins[reg][0];
#pragma unroll
    for (int r = 1; r < 11; ++r) l += bins[reg][r];
    float inv = 1.f / l;
#pragma unroll
    for (int c = 0; c < 4; ++c) {
      float v = ctx[c][reg];
#pragma unroll
      for (int r = 0; r < 11; ++r) v = fmaf(bins[reg][r], krl[r][c * 16 + col], v);
      size_t oidx = (size_t)(b * 1024 + q0 + row) * 512 + h * 64 + c * 16 + col;
      if (f32) ((float*)out)[oidx] = v * inv;
      else ((u16*)out)[oidx] = f2bf(v * inv);
    }
  }
}

// ---------------------------------------------------------------------------
extern "C" void kernel_launch(void* const* d_in, const int* in_sizes, int n_in,
                              void* d_out, int out_size, void* d_ws, size_t ws_size,
                              hipStream_t stream) {
  const void* q = d_in[0];
  const void* k = d_in[1];
  const void* v = d_in[2];
  const int* rpr = (const int*)d_in[3];
  const void* wq = d_in[4];
  const void* bq = d_in[5];
  const void* wk = d_in[6];
  const void* bk = d_in[7];
  const void* wv = d_in[8];
  const void* bv = d_in[9];
  const void* krpr = d_in[10];

  int* flag = (int*)d_ws;
  u16* ws = (u16*)((char*)d_ws + 1024);  // bf16 ws: 12.6 MB (validated r10)

  // Host-side dtype: q is B*S*D = 2,097,152 elements. If in_sizes[0] is a
  // byte count it is 4194304 (bf16) or 8388608 (f32) — decisive. Any other
  // value (e.g. an element-count convention) -> proj detects locally and
  // publishes the flag for attn (detect kernel deleted this round).
  int hflag = -1;
  if (in_sizes && n_in > 0) {
    if (in_sizes[0] == 4194304) hflag = 0;        // bf16 input
    else if (in_sizes[0] == 8388608) hflag = 1;   // f32 input
  }

  rpr_proj_mfma<u16><<<dim3(8, 64, 3), 256, 0, stream>>>(
      q, k, v, wq, wk, wv, bq, bk, bv, ws, flag, hflag);
  rpr_attn_mfma<u16><<<dim3(16, 32), 256, 0, stream>>>(
      ws, rpr, krpr, d_out, flag, hflag);
}